// Round 17
// baseline (102.279 us; speedup 1.0000x reference)
//
#include <hip/hip_runtime.h>
#include <math.h>

#define NN 8192
#define MM 4096
#define DD 128
#define TDIM 32
#define H1DIM 64
#define H2DIM 32
#define FEAT (3*DD + TDIM)   // 416
#define KGROUPS (FEAT/4)     // 104
#define BIGF 1e30f

#define NCHUNK 512           // scan blocks; block c owns rows [16c,16c+16)
#define RPC 16
#define CAP 8                // members per (chunk,edge); P(overflow)~1e-13
#define LISTCAP 256
#define EDGES 16             // edges per stats block (= group size)
#define NGRP (MM/EDGES)      // 256 groups

// ---- stats/MLP kernel LDS layout (bytes) ----
#define LDS_W1P   0
#define LDS_W2T   106496
#define LDS_LSF   114688
#define LDS_HS1   141312
#define LDS_LISTS 145408
#define LDS_LCNT  153600
#define LDS_TOTAL 153664

typedef float fvec4 __attribute__((ext_vector_type(4)));

// ===== MEASUREMENT ROUND 3: isolate per-node launch overhead L =====
// Pipeline identical to R16 + 32 empty-kernel nodes. L = (dur - 52.75)/32.

__global__ void empty_probe(int* __restrict__ dummy) {
    if (blockIdx.x == 0x7FFFFFF0)            // never true
        dummy[threadIdx.x] = 1;
}

__global__ __launch_bounds__(256) void scan_csc(
        const float* __restrict__ H,
        unsigned short* __restrict__ idxg, unsigned char* __restrict__ cntg) {
    __shared__ int lcnt[MM];                 // 16 KB
    const int tid = threadIdx.x;
    const int c   = blockIdx.x;
    for (int i = tid; i < MM; i += 256) lcnt[i] = 0;
    __syncthreads();

    const fvec4* H4 = reinterpret_cast<const fvec4*>(H) + (size_t)c * (RPC * MM / 4);
    const int r0 = c * RPC;

    for (int s = 0; s < 8; ++s) {            // 64 float4/thread, 8-deep batches
        fvec4 a[8]; int o[8];
        #pragma unroll
        for (int u = 0; u < 8; ++u) {
            o[u] = s * 2048 + u * 256 + tid;
            a[u] = H4[o[u]];
        }
        #pragma unroll
        for (int u = 0; u < 8; ++u) {
            fvec4 v = a[u];
            if (v.x != 0.f || v.y != 0.f || v.z != 0.f || v.w != 0.f) {
                int r  = r0 + (o[u] >> 10);          // 1024 float4s per row
                int mb = (o[u] & 1023) * 4;
                float vals[4] = {v.x, v.y, v.z, v.w};
                #pragma unroll
                for (int q = 0; q < 4; ++q) {
                    if (vals[q] != 0.0f) {
                        int m = mb + q;
                        int p = atomicAdd(&lcnt[m], 1);
                        if (p < CAP) {
                            size_t cell = ((size_t)(m >> 4) * NCHUNK + c) * EDGES
                                          + (m & 15);
                            idxg[cell * CAP + p] = (unsigned short)r;
                        }
                    }
                }
            }
        }
    }
    __syncthreads();

    {
        int g = tid;                                  // 256 threads = 256 groups
        unsigned int w[4];
        #pragma unroll
        for (int q = 0; q < 4; ++q) {
            unsigned int k0 = min(lcnt[g*16 + 4*q + 0], CAP);
            unsigned int k1 = min(lcnt[g*16 + 4*q + 1], CAP);
            unsigned int k2 = min(lcnt[g*16 + 4*q + 2], CAP);
            unsigned int k3 = min(lcnt[g*16 + 4*q + 3], CAP);
            w[q] = k0 | (k1 << 8) | (k2 << 16) | (k3 << 24);
        }
        uint4* dst = (uint4*)(cntg + ((size_t)g * NCHUNK + c) * EDGES);
        *dst = make_uint4(w[0], w[1], w[2], w[3]);
    }
}

__global__ __launch_bounds__(1024, 1) void stats_mlp(
        const float* __restrict__ x,
        const unsigned short* __restrict__ idxg, const unsigned char* __restrict__ cntg,
        const float* __restrict__ tptr, const float* __restrict__ Wt,
        const float* __restrict__ bt,
        const float* __restrict__ W1, const float* __restrict__ b1,
        const float* __restrict__ W2, const float* __restrict__ b2,
        const float* __restrict__ W3, const float* __restrict__ b3,
        float* __restrict__ out) {
    extern __shared__ char smem[];
    float*          w1p   = (float*)(smem + LDS_W1P);
    float*          w2t   = (float*)(smem + LDS_W2T);
    float*          lsf   = (float*)(smem + LDS_LSF);
    float*          hs1   = (float*)(smem + LDS_HS1);
    unsigned short* lists = (unsigned short*)(smem + LDS_LISTS);
    int*            lcnt2 = (int*)(smem + LDS_LCNT);

    const int tid = threadIdx.x;
    const int wv  = tid >> 6, lane = tid & 63;
    const int g   = blockIdx.x;
    const int m0  = g * EDGES;

    for (int i = tid; i < FEAT * H1DIM; i += 1024) {
        float v = W1[i];
        int j = i / FEAT, k = i - j * FEAT;
        w1p[(k >> 2) * (H1DIM * 4) + j * 4 + (k & 3)] = v;
    }
    for (int i = tid; i < H1DIM * H2DIM; i += 1024) {
        w2t[(i & 63) * H2DIM + (i >> 6)] = W2[i];
    }
    if (tid < EDGES) lcnt2[tid] = 0;
    __syncthreads();

    {
        const int c  = tid >> 1;
        const int e0 = (tid & 1) * 8;
        const size_t cellbase = ((size_t)g * NCHUNK + c) * EDGES + e0;
        unsigned long long k8 = *reinterpret_cast<const unsigned long long*>(
                                    cntg + cellbase);
        if (k8) {
            #pragma unroll
            for (int j = 0; j < 8; ++j) {
                int k = (int)((k8 >> (8 * j)) & 0xFF);
                if (k) {
                    uint4 s = *reinterpret_cast<const uint4*>(
                                  idxg + (cellbase + j) * CAP);
                    int e = e0 + j;
                    int base = atomicAdd(&lcnt2[e], k);
                    if (base + 8 <= LISTCAP) {
                        unsigned short* dst = &lists[e * LISTCAP + base];
                        dst[0] = (unsigned short)(s.x & 0xFFFF);
                        if (k > 1) dst[1] = (unsigned short)(s.x >> 16);
                        if (k > 2) dst[2] = (unsigned short)(s.y & 0xFFFF);
                        if (k > 3) dst[3] = (unsigned short)(s.y >> 16);
                        if (k > 4) dst[4] = (unsigned short)(s.z & 0xFFFF);
                        if (k > 5) dst[5] = (unsigned short)(s.z >> 16);
                        if (k > 6) dst[6] = (unsigned short)(s.w & 0xFFFF);
                        if (k > 7) dst[7] = (unsigned short)(s.w >> 16);
                    }
                }
            }
        }
    }
    __syncthreads();

    {
        const float tval = tptr[0];
        int K = lcnt2[wv]; if (K > LISTCAP) K = LISTCAP;
        const unsigned short* lst = lists + wv * LISTCAP;
        float sx = 0.f, sy = 0.f, s2x = 0.f, s2y = 0.f;
        float mxx = -BIGF, mxy = -BIGF, mnx = BIGF, mny = BIGF;
        const float* xb = x + 2 * lane;
        int i = 0;
        for (; i + 4 <= K; i += 4) {
            ushort4 nv = *reinterpret_cast<const ushort4*>(lst + i);
            float2 v0 = *reinterpret_cast<const float2*>(xb + (int)nv.x * DD);
            float2 v1 = *reinterpret_cast<const float2*>(xb + (int)nv.y * DD);
            float2 v2 = *reinterpret_cast<const float2*>(xb + (int)nv.z * DD);
            float2 v3 = *reinterpret_cast<const float2*>(xb + (int)nv.w * DD);
            sx  += (v0.x + v1.x) + (v2.x + v3.x);
            sy  += (v0.y + v1.y) + (v2.y + v3.y);
            s2x += (v0.x*v0.x + v1.x*v1.x) + (v2.x*v2.x + v3.x*v3.x);
            s2y += (v0.y*v0.y + v1.y*v1.y) + (v2.y*v2.y + v3.y*v3.y);
            mxx = fmaxf(mxx, fmaxf(fmaxf(v0.x, v1.x), fmaxf(v2.x, v3.x)));
            mxy = fmaxf(mxy, fmaxf(fmaxf(v0.y, v1.y), fmaxf(v2.y, v3.y)));
            mnx = fminf(mnx, fminf(fminf(v0.x, v1.x), fminf(v2.x, v3.x)));
            mny = fminf(mny, fminf(fminf(v0.y, v1.y), fminf(v2.y, v3.y)));
        }
        for (; i < K; ++i) {
            float2 v = *reinterpret_cast<const float2*>(xb + (int)lst[i] * DD);
            sx += v.x; sy += v.y; s2x += v.x*v.x; s2y += v.y*v.y;
            mxx = fmaxf(mxx, v.x); mxy = fmaxf(mxy, v.y);
            mnx = fminf(mnx, v.x); mny = fminf(mny, v.y);
        }
        float deg = (K > 0) ? (float)K : 1.0f;
        float mux = sx / deg, muy = sy / deg;
        float sgx = sqrtf(fmaxf(s2x / deg - mux * mux, 1e-8f));
        float sgy = sqrtf(fmaxf(s2y / deg - muy * muy, 1e-8f));
        float dlx = (K > 0) ? (mxx - mnx) : 0.0f;
        float dly = (K > 0) ? (mxy - mny) : 0.0f;
        float* f = lsf + wv * FEAT;
        f[2*lane]          = mux;  f[2*lane + 1]        = muy;
        f[DD + 2*lane]     = sgx;  f[DD + 2*lane + 1]   = sgy;
        f[2*DD + 2*lane]   = dlx;  f[2*DD + 2*lane + 1] = dly;
        if (lane < TDIM)
            f[3*DD + lane] = fmaxf(tval * Wt[lane] + bt[lane], 0.0f);
    }
    __syncthreads();

    {
        const float4* W1P4 = reinterpret_cast<const float4*>(w1p);
        const float4* fr   = reinterpret_cast<const float4*>(lsf + wv * FEAT);
        float acc = b1[lane];
        #pragma unroll 8
        for (int g2 = 0; g2 < KGROUPS; ++g2) {
            float4 w = W1P4[g2 * H1DIM + lane];
            float4 a = fr[g2];
            acc += a.x*w.x + a.y*w.y + a.z*w.z + a.w*w.w;
        }
        hs1[wv * H1DIM + lane] = fmaxf(acc, 0.f);
        const int j2 = lane & 31;
        const int kh = (lane >> 5) * 32;
        float a2 = 0.f;
        #pragma unroll
        for (int kk = 0; kk < 32; ++kk) {
            int k = kh + kk;
            a2 += hs1[wv * H1DIM + k] * w2t[k * H2DIM + j2];
        }
        a2 += __shfl_xor(a2, 32);
        float h2 = fmaxf(a2 + b2[j2], 0.f);
        float p = h2 * W3[j2];
        p += __shfl_xor(p, 16);
        p += __shfl_xor(p, 8);
        p += __shfl_xor(p, 4);
        p += __shfl_xor(p, 2);
        p += __shfl_xor(p, 1);
        if (lane == 0) out[m0 + wv] = 1.f / (1.f + expf(-(p + b3[0])));
    }
}

extern "C" void kernel_launch(void* const* d_in, const int* in_sizes, int n_in,
                              void* d_out, int out_size, void* d_ws, size_t ws_size,
                              hipStream_t stream) {
    const float* x   = (const float*)d_in[0];
    const float* H   = (const float*)d_in[1];
    const float* t   = (const float*)d_in[2];
    const float* Wt  = (const float*)d_in[3];
    const float* bt  = (const float*)d_in[4];
    const float* W1  = (const float*)d_in[5];
    const float* b1  = (const float*)d_in[6];
    const float* W2  = (const float*)d_in[7];
    const float* b2  = (const float*)d_in[8];
    const float* W3  = (const float*)d_in[9];
    const float* b3  = (const float*)d_in[10];
    float* out = (float*)d_out;

    unsigned short* idxg = (unsigned short*)d_ws;
    unsigned char*  cntg = (unsigned char*)(idxg + (size_t)NGRP * NCHUNK * EDGES * CAP);
    int* dummy = (int*)(cntg + (size_t)NGRP * NCHUNK * EDGES);

    hipFuncSetAttribute((const void*)stats_mlp,
                        hipFuncAttributeMaxDynamicSharedMemorySize, LDS_TOTAL);

    scan_csc<<<NCHUNK, 256, 0, stream>>>(H, idxg, cntg);
    stats_mlp<<<NGRP, 1024, LDS_TOTAL, stream>>>(
        x, idxg, cntg, t, Wt, bt, W1, b1, W2, b2, W3, b3, out);
    // 32 empty nodes: marginal cost = 32 x per-node launch overhead L.
    for (int rep = 0; rep < 32; ++rep) {
        empty_probe<<<NCHUNK, 256, 0, stream>>>(dummy);
    }
}

// Round 18
// 56.942 us; speedup vs baseline: 1.7962x; 1.7962x over previous
//
#include <hip/hip_runtime.h>
#include <math.h>

#define NN 8192
#define MM 4096
#define DD 128
#define TDIM 32
#define H1DIM 64
#define H2DIM 32
#define FEAT (3*DD + TDIM)   // 416
#define KGROUPS (FEAT/4)     // 104
#define BIGF 1e30f

#define NCHUNK 512           // scan blocks; block c owns rows [16c,16c+16)
#define RPC 16
#define CAP 8                // members per (chunk,edge); P(overflow)~1e-13
#define LISTCAP 256
#define EDGES 16             // edges per stats block (= group size)
#define NGRP (MM/EDGES)      // 256 groups

typedef float fvec4 __attribute__((ext_vector_type(4)));

// Node 1: chunked CSC scan, group-major output (R16-proven; warm scan =
// 20.7 us = 134 MB @ 6.5 TB/s = HBM ceiling). Extra block NCHUNK packs
// W1->W1P / W2->W2T in global, hidden under the scan (R12-proven).
__global__ __launch_bounds__(256) void scan_csc(
        const float* __restrict__ H,
        const float* __restrict__ W1, const float* __restrict__ W2,
        unsigned short* __restrict__ idxg, unsigned char* __restrict__ cntg,
        float* __restrict__ W1P, float* __restrict__ W2T) {
    const int tid = threadIdx.x;
    const int c   = blockIdx.x;
    if (c == NCHUNK) {                       // pack block
        for (int i = tid; i < FEAT * H1DIM; i += 256) {
            int cc = i & 3, j = (i >> 2) & 63, g = i >> 8;
            W1P[i] = W1[j * FEAT + g * 4 + cc];   // W1P4[g*64+j] = W1[j][4g..]
        }
        for (int i = tid; i < H1DIM * H2DIM; i += 256) {
            W2T[i] = W2[(i & 31) * H1DIM + (i >> 5)];  // w2t[k*32+j2]
        }
        return;
    }

    __shared__ int lcnt[MM];                 // 16 KB
    for (int i = tid; i < MM; i += 256) lcnt[i] = 0;
    __syncthreads();

    const fvec4* H4 = reinterpret_cast<const fvec4*>(H) + (size_t)c * (RPC * MM / 4);
    const int r0 = c * RPC;

    for (int s = 0; s < 8; ++s) {            // 64 float4/thread, 8-deep batches
        fvec4 a[8]; int o[8];
        #pragma unroll
        for (int u = 0; u < 8; ++u) {
            o[u] = s * 2048 + u * 256 + tid;
            a[u] = H4[o[u]];
        }
        #pragma unroll
        for (int u = 0; u < 8; ++u) {
            fvec4 v = a[u];
            if (v.x != 0.f || v.y != 0.f || v.z != 0.f || v.w != 0.f) {
                int r  = r0 + (o[u] >> 10);          // 1024 float4s per row
                int mb = (o[u] & 1023) * 4;
                float vals[4] = {v.x, v.y, v.z, v.w};
                #pragma unroll
                for (int q = 0; q < 4; ++q) {
                    if (vals[q] != 0.0f) {
                        int m = mb + q;
                        int p = atomicAdd(&lcnt[m], 1);
                        if (p < CAP) {
                            size_t cell = ((size_t)(m >> 4) * NCHUNK + c) * EDGES
                                          + (m & 15);
                            idxg[cell * CAP + p] = (unsigned short)r;
                        }
                    }
                }
            }
        }
    }
    __syncthreads();

    {
        int g = tid;                                  // 256 threads = 256 groups
        unsigned int w[4];
        #pragma unroll
        for (int q = 0; q < 4; ++q) {
            unsigned int k0 = min(lcnt[g*16 + 4*q + 0], CAP);
            unsigned int k1 = min(lcnt[g*16 + 4*q + 1], CAP);
            unsigned int k2 = min(lcnt[g*16 + 4*q + 2], CAP);
            unsigned int k3 = min(lcnt[g*16 + 4*q + 3], CAP);
            w[q] = k0 | (k1 << 8) | (k2 << 16) | (k3 << 24);
        }
        uint4* dst = (uint4*)(cntg + ((size_t)g * NCHUNK + c) * EDGES);
        *dst = make_uint4(w[0], w[1], w[2], w[3]);
    }
}

// Node 2: merge + stats + MLP. 256 blocks x 1024 thr, ~39 KB static LDS.
//   B1: group-major merge (R16-proven, one uint4/segment)
//   B2: per-wave stats (proven float2 gathers)
//   B3: SPLIT-PIPE MLP (R6-proven shape): waves 0-3 x 4 rows; W1P fragment
//       from GLOBAL (L1/L2 pipe, coalesced, grid-shared -> L2-hot); feature
//       broadcasts from LDS. Halves the LDS-pipe instruction count that
//       bound R10/R16's B3.
__global__ __launch_bounds__(1024) void stats_mlp(
        const float* __restrict__ x,
        const unsigned short* __restrict__ idxg, const unsigned char* __restrict__ cntg,
        const float* __restrict__ tptr, const float* __restrict__ Wt,
        const float* __restrict__ bt,
        const float* __restrict__ W1P, const float* __restrict__ b1,
        const float* __restrict__ W2T, const float* __restrict__ b2,
        const float* __restrict__ W3, const float* __restrict__ b3,
        float* __restrict__ out) {
    __shared__ float lsf[EDGES][FEAT];               // 26624 B
    __shared__ float hs1[EDGES][H1DIM];              //  4096 B
    __shared__ unsigned short lists[EDGES][LISTCAP]; //  8192 B
    __shared__ int lcnt2[EDGES];

    const int tid = threadIdx.x;
    const int wv  = tid >> 6, lane = tid & 63;
    const int g   = blockIdx.x;
    const int m0  = g * EDGES;

    if (tid < EDGES) lcnt2[tid] = 0;
    __syncthreads();

    // ---- B1: merge group-major chunk segments into per-edge LDS lists ----
    {
        const int c  = tid >> 1;               // chunk (0..511)
        const int e0 = (tid & 1) * 8;          // edge octet
        const size_t cellbase = ((size_t)g * NCHUNK + c) * EDGES + e0;
        unsigned long long k8 = *reinterpret_cast<const unsigned long long*>(
                                    cntg + cellbase);     // contiguous 8B
        if (k8) {
            #pragma unroll
            for (int j = 0; j < 8; ++j) {
                int k = (int)((k8 >> (8 * j)) & 0xFF);
                if (k) {
                    uint4 s = *reinterpret_cast<const uint4*>(
                                  idxg + (cellbase + j) * CAP);  // one 16B load
                    int e = e0 + j;
                    int base = atomicAdd(&lcnt2[e], k);
                    if (base + 8 <= LISTCAP) {
                        unsigned short* dst = &lists[e][base];
                        dst[0] = (unsigned short)(s.x & 0xFFFF);
                        if (k > 1) dst[1] = (unsigned short)(s.x >> 16);
                        if (k > 2) dst[2] = (unsigned short)(s.y & 0xFFFF);
                        if (k > 3) dst[3] = (unsigned short)(s.y >> 16);
                        if (k > 4) dst[4] = (unsigned short)(s.z & 0xFFFF);
                        if (k > 5) dst[5] = (unsigned short)(s.z >> 16);
                        if (k > 6) dst[6] = (unsigned short)(s.w & 0xFFFF);
                        if (k > 7) dst[7] = (unsigned short)(s.w >> 16);
                    }
                }
            }
        }
    }
    __syncthreads();

    // ---- B2: stats (wave wv -> edge wv) ----
    {
        const float tval = tptr[0];
        int K = lcnt2[wv]; if (K > LISTCAP) K = LISTCAP;
        const unsigned short* lst = lists[wv];
        float sx = 0.f, sy = 0.f, s2x = 0.f, s2y = 0.f;
        float mxx = -BIGF, mxy = -BIGF, mnx = BIGF, mny = BIGF;
        const float* xb = x + 2 * lane;
        int i = 0;
        for (; i + 4 <= K; i += 4) {
            ushort4 nv = *reinterpret_cast<const ushort4*>(lst + i);
            float2 v0 = *reinterpret_cast<const float2*>(xb + (int)nv.x * DD);
            float2 v1 = *reinterpret_cast<const float2*>(xb + (int)nv.y * DD);
            float2 v2 = *reinterpret_cast<const float2*>(xb + (int)nv.z * DD);
            float2 v3 = *reinterpret_cast<const float2*>(xb + (int)nv.w * DD);
            sx  += (v0.x + v1.x) + (v2.x + v3.x);
            sy  += (v0.y + v1.y) + (v2.y + v3.y);
            s2x += (v0.x*v0.x + v1.x*v1.x) + (v2.x*v2.x + v3.x*v3.x);
            s2y += (v0.y*v0.y + v1.y*v1.y) + (v2.y*v2.y + v3.y*v3.y);
            mxx = fmaxf(mxx, fmaxf(fmaxf(v0.x, v1.x), fmaxf(v2.x, v3.x)));
            mxy = fmaxf(mxy, fmaxf(fmaxf(v0.y, v1.y), fmaxf(v2.y, v3.y)));
            mnx = fminf(mnx, fminf(fminf(v0.x, v1.x), fminf(v2.x, v3.x)));
            mny = fminf(mny, fminf(fminf(v0.y, v1.y), fminf(v2.y, v3.y)));
        }
        for (; i < K; ++i) {
            float2 v = *reinterpret_cast<const float2*>(xb + (int)lst[i] * DD);
            sx += v.x; sy += v.y; s2x += v.x*v.x; s2y += v.y*v.y;
            mxx = fmaxf(mxx, v.x); mxy = fmaxf(mxy, v.y);
            mnx = fminf(mnx, v.x); mny = fminf(mny, v.y);
        }
        float deg = (K > 0) ? (float)K : 1.0f;
        float mux = sx / deg, muy = sy / deg;
        float sgx = sqrtf(fmaxf(s2x / deg - mux * mux, 1e-8f));
        float sgy = sqrtf(fmaxf(s2y / deg - muy * muy, 1e-8f));
        float dlx = (K > 0) ? (mxx - mnx) : 0.0f;
        float dly = (K > 0) ? (mxy - mny) : 0.0f;
        float* f = lsf[wv];
        f[2*lane]          = mux;  f[2*lane + 1]        = muy;
        f[DD + 2*lane]     = sgx;  f[DD + 2*lane + 1]   = sgy;
        f[2*DD + 2*lane]   = dlx;  f[2*DD + 2*lane + 1] = dly;
        if (lane < TDIM)
            f[3*DD + lane] = fmaxf(tval * Wt[lane] + bt[lane], 0.0f);
    }
    __syncthreads();

    // ---- B3: split-pipe MLP (waves 0-3, 4 rows each) ----
    if (wv < 4) {
        const float4* W1P4 = reinterpret_cast<const float4*>(W1P);
        const int r0 = wv * 4;
        const float4* f0 = reinterpret_cast<const float4*>(lsf[r0 + 0]);
        const float4* f1 = reinterpret_cast<const float4*>(lsf[r0 + 1]);
        const float4* f2 = reinterpret_cast<const float4*>(lsf[r0 + 2]);
        const float4* f3 = reinterpret_cast<const float4*>(lsf[r0 + 3]);

        float bb = b1[lane];
        float acc0 = bb, acc1 = bb, acc2 = bb, acc3 = bb;
        #pragma unroll 4
        for (int gg = 0; gg < KGROUPS; ++gg) {
            float4 w = W1P4[gg * H1DIM + lane];   // GLOBAL: L1/L2 pipe
            float4 a0 = f0[gg];                    // LDS broadcasts
            float4 a1 = f1[gg];
            float4 a2 = f2[gg];
            float4 a3 = f3[gg];
            acc0 += a0.x*w.x + a0.y*w.y + a0.z*w.z + a0.w*w.w;
            acc1 += a1.x*w.x + a1.y*w.y + a1.z*w.z + a1.w*w.w;
            acc2 += a2.x*w.x + a2.y*w.y + a2.z*w.z + a2.w*w.w;
            acc3 += a3.x*w.x + a3.y*w.y + a3.z*w.z + a3.w*w.w;
        }
        hs1[r0 + 0][lane] = fmaxf(acc0, 0.f);
        hs1[r0 + 1][lane] = fmaxf(acc1, 0.f);
        hs1[r0 + 2][lane] = fmaxf(acc2, 0.f);
        hs1[r0 + 3][lane] = fmaxf(acc3, 0.f);

        const int j2 = lane & 31;
        const int kh = (lane >> 5) * 32;
        float w3v = W3[j2];
        float b2v = b2[j2];
        #pragma unroll
        for (int r = 0; r < 4; ++r) {
            const float* h1 = hs1[r0 + r];
            float a2 = 0.f;
            #pragma unroll
            for (int kk = 0; kk < 32; ++kk) {
                int k = kh + kk;
                a2 += h1[k] * W2T[k * H2DIM + j2];   // LDS bcast x global
            }
            a2 += __shfl_xor(a2, 32);
            float h2 = fmaxf(a2 + b2v, 0.f);
            float p = h2 * w3v;
            p += __shfl_xor(p, 16);
            p += __shfl_xor(p, 8);
            p += __shfl_xor(p, 4);
            p += __shfl_xor(p, 2);
            p += __shfl_xor(p, 1);
            if (lane == 0) out[m0 + r0 + r] = 1.f / (1.f + expf(-(p + b3[0])));
        }
    }
}

extern "C" void kernel_launch(void* const* d_in, const int* in_sizes, int n_in,
                              void* d_out, int out_size, void* d_ws, size_t ws_size,
                              hipStream_t stream) {
    const float* x   = (const float*)d_in[0];   // (N, D)
    const float* H   = (const float*)d_in[1];   // (N, M)
    const float* t   = (const float*)d_in[2];   // (1,)
    const float* Wt  = (const float*)d_in[3];   // (TDIM, 1)
    const float* bt  = (const float*)d_in[4];   // (TDIM,)
    const float* W1  = (const float*)d_in[5];   // (64, 416)
    const float* b1  = (const float*)d_in[6];
    const float* W2  = (const float*)d_in[7];   // (32, 64)
    const float* b2  = (const float*)d_in[8];
    const float* W3  = (const float*)d_in[9];   // (1, 32)
    const float* b3  = (const float*)d_in[10];
    float* out = (float*)d_out;

    // workspace: idxg 32 MB; cntg 2 MB; W1P 104 KB; W2T 8 KB
    unsigned short* idxg = (unsigned short*)d_ws;
    unsigned char*  cntg = (unsigned char*)(idxg + (size_t)NGRP * NCHUNK * EDGES * CAP);
    float*          W1P  = (float*)(cntg + (size_t)NGRP * NCHUNK * EDGES);
    float*          W2T  = W1P + FEAT * H1DIM;

    scan_csc<<<NCHUNK + 1, 256, 0, stream>>>(H, W1, W2, idxg, cntg, W1P, W2T);
    stats_mlp<<<NGRP, 1024, 0, stream>>>(
        x, idxg, cntg, t, Wt, bt, W1P, b1, W2T, b2, W3, b3, out);
}